// Round 1
// baseline (874.228 us; speedup 1.0000x reference)
//
#include <hip/hip_runtime.h>
#include <math.h>

#define B_ 32
#define N_ 64
#define K_ 128
#define NPAIR (B_*N_*N_)

__device__ __forceinline__ float silu_f(float x) {
    return x / (1.0f + expf(-x));
}

// ---------------------------------------------------------------------------
// Kernel 1: per-pair geometry -> rad[8], Y1[3], Y2[5], maskf
// ---------------------------------------------------------------------------
__global__ __launch_bounds__(256) void geom_kernel(
    const float* __restrict__ pos, const float* __restrict__ cell,
    float* __restrict__ rad, float* __restrict__ Y1, float* __restrict__ Y2,
    float* __restrict__ maskf)
{
    int p = blockIdx.x * 256 + threadIdx.x;
    if (p >= NPAIR) return;
    int b = p >> 12;        // / (64*64)
    int ij = p & 4095;
    int i = ij >> 6, j = ij & 63;
    const float* pi = pos + (size_t)(b*N_ + i)*3;
    const float* pj = pos + (size_t)(b*N_ + j)*3;
    float d0 = pi[0]-pj[0], d1 = pi[1]-pj[1], d2 = pi[2]-pj[2];
    d0 -= rintf(d0); d1 -= rintf(d1); d2 -= rintf(d2);   // jnp.round = half-even = rintf
    const float* C = cell + b*9;
    float dc0 = d0*C[0] + d1*C[3] + d2*C[6];
    float dc1 = d0*C[1] + d1*C[4] + d2*C[7];
    float dc2 = d0*C[2] + d1*C[5] + d2*C[8];
    float r2 = fmaxf(dc0*dc0 + dc1*dc1 + dc2*dc2, 1e-12f);
    float r = sqrtf(r2);
    bool m = (r < 5.0f) && (i != j);
    float mf = m ? 1.0f : 0.0f;
    float rs = m ? r : 1.0f;
    float inv_rs = 1.0f / rs;
    float x = dc0*inv_rs*mf, y = dc1*inv_rs*mf, z = dc2*inv_rs*mf;
    // polynomial cutoff fc(u), u = r/R_MAX, p=5: 1 - 21u^5 + 35u^6 - 15u^7
    float u = r * 0.2f;
    float u2 = u*u, u4 = u2*u2, u5 = u4*u;
    float fc = 1.0f - 21.0f*u5 + 35.0f*u5*u - 15.0f*u5*u2;
    fc = (u < 1.0f) ? fc : 0.0f;
    float pref = 0.6324555320336759f * inv_rs * (fc * mf);   // sqrt(2/5) / r * fc * mask
    float w = 0.6283185307179586f * rs;                      // (pi/5) * r_safe
    #pragma unroll
    for (int n = 1; n <= 8; n++)
        rad[(size_t)p*8 + (n-1)] = pref * sinf((float)n * w);
    const float s3  = 1.7320508075688772f;
    const float s5  = 2.23606797749979f;
    const float s15 = 3.872983346207417f;
    float* y1 = Y1 + (size_t)p*3;
    y1[0] = s3*x; y1[1] = s3*y; y1[2] = s3*z;
    float* y2 = Y2 + (size_t)p*5;
    y2[0] = s15*x*y;
    y2[1] = s15*y*z;
    y2[2] = 0.5f*s5*(3.0f*z*z - 1.0f);
    y2[3] = s15*x*z;
    y2[4] = 0.5f*s15*(x*x - y*y);
    maskf[p] = mf;
}

// ---------------------------------------------------------------------------
// Kernel 2 (pass 1): one block per node (b,i).
// Radial MLP1 (64 j-rows, 8->64->64->64 in LDS), then FACTORED last layer:
//   G[m,h] = sum_j Ym[j]*mask[j]*hc[j,h]   (9x64)
//   msg[m,k] = (sum_h G[m,h]*w3[h, c(m)*K+k] + SY[m]*b3) * w_embed[k] / 16
// Then s1, v1, h1=silu(s1); write feats[0:512], h1, v1.
// ---------------------------------------------------------------------------
__global__ __launch_bounds__(256) void pass1_kernel(
    const float* __restrict__ rad, const float* __restrict__ Y1g,
    const float* __restrict__ Y2g, const float* __restrict__ maskg,
    const float* __restrict__ wemb,
    const float* __restrict__ w0, const float* __restrict__ b0,
    const float* __restrict__ w1, const float* __restrict__ b1,
    const float* __restrict__ w2, const float* __restrict__ b2,
    const float* __restrict__ w3, const float* __restrict__ b3,
    const float* __restrict__ l0, const float* __restrict__ l1,
    const float* __restrict__ l2, const float* __restrict__ timeg,
    float* __restrict__ h1g, float* __restrict__ v1g, float* __restrict__ featsg)
{
    __shared__ float ha[64*64];
    __shared__ float hb[64*64];
    __shared__ float rad_s[64*8];
    __shared__ float Ym[9*64];
    __shared__ float G[9*64];
    __shared__ float SY[9];
    __shared__ float msg[9*128];
    __shared__ float q[128];
    int t = threadIdx.x;
    int node = blockIdx.x;           // b*64 + i
    int b = node >> 6;
    size_t pbase = (size_t)node * 64;

    for (int idx = t; idx < 512; idx += 256) rad_s[idx] = rad[pbase*8 + idx];
    if (t < 64) {
        int j = t;
        float mf = maskg[pbase + j];
        Ym[0*64+j] = mf;                                 // Y0 = 1
        #pragma unroll
        for (int m = 0; m < 3; m++) Ym[(1+m)*64+j] = Y1g[(pbase+j)*3+m]*mf;
        #pragma unroll
        for (int m = 0; m < 5; m++) Ym[(4+m)*64+j] = Y2g[(pbase+j)*5+m]*mf;
    }
    __syncthreads();

    // layer 0: 8 -> 64
    for (int idx = t; idx < 4096; idx += 256) {
        int j = idx >> 6, h = idx & 63;
        float acc = b0[h];
        #pragma unroll
        for (int c = 0; c < 8; c++) acc += rad_s[j*8+c] * w0[c*64+h];
        ha[idx] = silu_f(acc);
    }
    __syncthreads();
    // layer 1: 64 -> 64
    for (int idx = t; idx < 4096; idx += 256) {
        int j = idx >> 6, h = idx & 63;
        float acc = b1[h];
        #pragma unroll 8
        for (int k = 0; k < 64; k++) acc += ha[j*64+k] * w1[k*64+h];
        hb[idx] = silu_f(acc);
    }
    __syncthreads();
    // layer 2: 64 -> 64  (hc lands in ha)
    for (int idx = t; idx < 4096; idx += 256) {
        int j = idx >> 6, h = idx & 63;
        float acc = b2[h];
        #pragma unroll 8
        for (int k = 0; k < 64; k++) acc += hb[j*64+k] * w2[k*64+h];
        ha[idx] = silu_f(acc);
    }
    __syncthreads();

    if (t < 9) {
        float acc = 0.f;
        for (int j = 0; j < 64; j++) acc += Ym[t*64+j];
        SY[t] = acc;
    }
    for (int idx = t; idx < 576; idx += 256) {
        int m = idx >> 6, h = idx & 63;
        float acc = 0.f;
        #pragma unroll 8
        for (int j = 0; j < 64; j++) acc += Ym[m*64+j] * ha[j*64+h];
        G[idx] = acc;
    }
    __syncthreads();

    for (int idx = t; idx < 1152; idx += 256) {
        int m = idx >> 7, k = idx & 127;
        int c = (m == 0) ? 0 : ((m < 4) ? 1 : 2);
        int col = c*128 + k;
        float acc = SY[m] * b3[col];
        #pragma unroll 8
        for (int h = 0; h < 64; h++) acc += G[m*64+h] * w3[h*384+col];
        msg[m*128+k] = acc * wemb[k] * 0.0625f;   // * w_embed / AVG_NEIGH
    }
    __syncthreads();

    if (t < 128) {
        int k = t;
        float acc = 0.f;
        #pragma unroll
        for (int m = 4; m < 9; m++) { float v = msg[m*128+k]; acc += v*v; }
        q[k] = acc;
    }
    __syncthreads();

    for (int idx = t; idx < 512; idx += 256) {
        if (idx < 128) {
            int c = idx;
            float acc = 0.f;
            for (int k = 0; k < 128; k++)
                acc += msg[k]*l0[k*128+c] + q[k]*l2[k*128+c];
            featsg[(size_t)node*641 + c] = acc;            // s1
            h1g[(size_t)node*128 + c] = silu_f(acc);       // h1
        } else {
            int vi = idx - 128;
            int m = vi >> 7, c = vi & 127;
            float acc = 0.f;
            for (int k = 0; k < 128; k++) acc += msg[(1+m)*128+k]*l1[k*128+c];
            v1g[(size_t)node*384 + m*128 + c] = acc;       // v1
            featsg[(size_t)node*641 + 128 + m*128 + c] = acc;
        }
    }
    if (t == 0) featsg[(size_t)node*641 + 640] = timeg[b]; // time feature
}

// ---------------------------------------------------------------------------
// Kernel 3 (pass 2): one block per node (b,i).
// Radial MLP2 in LDS; we2 channels one at a time (64x128 in LDS);
// msg_a = sum_j we2_0[j,k]*h1[b,j,k];  inv[j,k] = sum_m Y1[i,j,m]*v1[b,j,m,k];
// msg_b = sum_j we2_1[j,k]*inv[j,k];  s2 = (msg_a+msg_b)/16 @ mix2.
// ---------------------------------------------------------------------------
__global__ __launch_bounds__(256) void pass2_kernel(
    const float* __restrict__ rad, const float* __restrict__ Y1g,
    const float* __restrict__ maskg,
    const float* __restrict__ w0, const float* __restrict__ b0,
    const float* __restrict__ w1, const float* __restrict__ b1,
    const float* __restrict__ w2, const float* __restrict__ b2,
    const float* __restrict__ w3, const float* __restrict__ b3,
    const float* __restrict__ mix2,
    const float* __restrict__ h1g, const float* __restrict__ v1g,
    float* __restrict__ featsg)
{
    __shared__ float buf[4096*3];     // ha=buf[0:4096], hb=buf[4096:8192], we=buf[4096:12288]
    __shared__ float rad_s[512];
    __shared__ float Y1s[64*3];
    __shared__ float mask_s[64];
    __shared__ float msgab[128];
    float* ha = buf;
    float* hb = buf + 4096;
    float* we = buf + 4096;
    int t = threadIdx.x;
    int node = blockIdx.x;
    int b = node >> 6;
    size_t pbase = (size_t)node * 64;

    for (int idx = t; idx < 512; idx += 256) rad_s[idx] = rad[pbase*8 + idx];
    if (t < 64) {
        mask_s[t] = maskg[pbase + t];
        #pragma unroll
        for (int m = 0; m < 3; m++) Y1s[t*3+m] = Y1g[(pbase+t)*3+m];
    }
    __syncthreads();

    for (int idx = t; idx < 4096; idx += 256) {     // layer 0
        int j = idx >> 6, h = idx & 63;
        float acc = b0[h];
        #pragma unroll
        for (int c = 0; c < 8; c++) acc += rad_s[j*8+c] * w0[c*64+h];
        ha[idx] = silu_f(acc);
    }
    __syncthreads();
    for (int idx = t; idx < 4096; idx += 256) {     // layer 1
        int j = idx >> 6, h = idx & 63;
        float acc = b1[h];
        #pragma unroll 8
        for (int k = 0; k < 64; k++) acc += ha[j*64+k] * w1[k*64+h];
        hb[idx] = silu_f(acc);
    }
    __syncthreads();
    for (int idx = t; idx < 4096; idx += 256) {     // layer 2 -> hc in ha
        int j = idx >> 6, h = idx & 63;
        float acc = b2[h];
        #pragma unroll 8
        for (int k = 0; k < 64; k++) acc += hb[j*64+k] * w2[k*64+h];
        ha[idx] = silu_f(acc);
    }
    __syncthreads();

    // channel 0 of we2
    for (int idx = t; idx < 8192; idx += 256) {
        int j = idx >> 7, k = idx & 127;
        float acc = b3[k];
        #pragma unroll 8
        for (int h = 0; h < 64; h++) acc += ha[j*64+h] * w3[h*256+k];
        we[idx] = acc * mask_s[j];
    }
    __syncthreads();
    if (t < 128) {
        int k = t;
        float acc = 0.f;
        for (int j = 0; j < 64; j++)
            acc += we[j*128+k] * h1g[((size_t)b*64 + j)*128 + k];
        msgab[k] = acc;
    }
    __syncthreads();

    // channel 1 of we2
    for (int idx = t; idx < 8192; idx += 256) {
        int j = idx >> 7, k = idx & 127;
        float acc = b3[128+k];
        #pragma unroll 8
        for (int h = 0; h < 64; h++) acc += ha[j*64+h] * w3[h*256+128+k];
        we[idx] = acc * mask_s[j];
    }
    __syncthreads();
    if (t < 128) {
        int k = t;
        float acc = 0.f;
        for (int j = 0; j < 64; j++) {
            const float* v = v1g + ((size_t)b*64 + j)*384 + k;
            float inv = Y1s[j*3+0]*v[0] + Y1s[j*3+1]*v[128] + Y1s[j*3+2]*v[256];
            acc += we[j*128+k] * inv;
        }
        msgab[k] += acc;
    }
    __syncthreads();

    if (t < 128) {
        int c = t;
        float acc = 0.f;
        for (int k = 0; k < 128; k++) acc += msgab[k] * mix2[k*128+c];
        featsg[(size_t)node*641 + 512 + c] = acc * 0.0625f;   // s2
    }
}

// ---------------------------------------------------------------------------
// Kernel 4: final MLP 641 -> 512 -> 512 -> 3, one block per node.
// ---------------------------------------------------------------------------
__global__ __launch_bounds__(256) void final_kernel(
    const float* __restrict__ featsg,
    const float* __restrict__ w0, const float* __restrict__ b0,
    const float* __restrict__ w1, const float* __restrict__ b1,
    const float* __restrict__ w2, const float* __restrict__ b2,
    float* __restrict__ out)
{
    __shared__ float xs[641];
    __shared__ float hs[512];
    __shared__ float red[3*256];
    int t = threadIdx.x;
    int node = blockIdx.x;
    for (int idx = t; idx < 641; idx += 256) xs[idx] = featsg[(size_t)node*641 + idx];
    __syncthreads();
    float a0 = b0[t], a1 = b0[t+256];
    for (int r = 0; r < 641; r++) {
        float xv = xs[r];
        a0 += xv * w0[r*512 + t];
        a1 += xv * w0[r*512 + t + 256];
    }
    hs[t] = fmaxf(a0, 0.f);
    hs[t+256] = fmaxf(a1, 0.f);
    __syncthreads();
    float c0 = b1[t], c1 = b1[t+256];
    for (int r = 0; r < 512; r++) {
        float hv = hs[r];
        c0 += hv * w1[r*512 + t];
        c1 += hv * w1[r*512 + t + 256];
    }
    c0 = fmaxf(c0, 0.f); c1 = fmaxf(c1, 0.f);
    // layer 2 partials: this thread owns hidden rows t and t+256
    red[t]       = c0 * w2[t*3+0] + c1 * w2[(t+256)*3+0];
    red[256+t]   = c0 * w2[t*3+1] + c1 * w2[(t+256)*3+1];
    red[512+t]   = c0 * w2[t*3+2] + c1 * w2[(t+256)*3+2];
    __syncthreads();
    for (int s = 128; s > 0; s >>= 1) {
        if (t < s) {
            red[t]     += red[t+s];
            red[256+t] += red[256+t+s];
            red[512+t] += red[512+t+s];
        }
        __syncthreads();
    }
    if (t < 3) out[(size_t)node*3 + t] = red[t*256] + b2[t];
}

extern "C" void kernel_launch(void* const* d_in, const int* in_sizes, int n_in,
                              void* d_out, int out_size, void* d_ws, size_t ws_size,
                              hipStream_t stream) {
    const float* pos   = (const float*)d_in[0];
    const float* timeg = (const float*)d_in[1];
    const float* cell  = (const float*)d_in[2];
    const float* wemb  = (const float*)d_in[3];
    const float* r1w0  = (const float*)d_in[4];
    const float* r1b0  = (const float*)d_in[5];
    const float* r1w1  = (const float*)d_in[6];
    const float* r1b1  = (const float*)d_in[7];
    const float* r1w2  = (const float*)d_in[8];
    const float* r1b2  = (const float*)d_in[9];
    const float* r1w3  = (const float*)d_in[10];
    const float* r1b3  = (const float*)d_in[11];
    const float* l0    = (const float*)d_in[12];
    const float* l1    = (const float*)d_in[13];
    const float* l2    = (const float*)d_in[14];
    const float* r2w0  = (const float*)d_in[15];
    const float* r2b0  = (const float*)d_in[16];
    const float* r2w1  = (const float*)d_in[17];
    const float* r2b1  = (const float*)d_in[18];
    const float* r2w2  = (const float*)d_in[19];
    const float* r2b2  = (const float*)d_in[20];
    const float* r2w3  = (const float*)d_in[21];
    const float* r2b3  = (const float*)d_in[22];
    const float* mix2  = (const float*)d_in[23];
    const float* mw0   = (const float*)d_in[24];
    const float* mb0   = (const float*)d_in[25];
    const float* mw1   = (const float*)d_in[26];
    const float* mb1   = (const float*)d_in[27];
    const float* mw2   = (const float*)d_in[28];
    const float* mb2   = (const float*)d_in[29];

    float* ws    = (float*)d_ws;
    float* rad   = ws;                                  // NPAIR*8
    float* Y1    = rad   + (size_t)NPAIR*8;             // NPAIR*3
    float* Y2    = Y1    + (size_t)NPAIR*3;             // NPAIR*5
    float* maskf = Y2    + (size_t)NPAIR*5;             // NPAIR
    float* h1    = maskf + (size_t)NPAIR;               // B*N*K
    float* v1    = h1    + (size_t)B_*N_*K_;            // B*N*3*K
    float* feats = v1    + (size_t)B_*N_*3*K_;          // B*N*641

    geom_kernel<<<NPAIR/256, 256, 0, stream>>>(pos, cell, rad, Y1, Y2, maskf);
    pass1_kernel<<<B_*N_, 256, 0, stream>>>(rad, Y1, Y2, maskf, wemb,
        r1w0, r1b0, r1w1, r1b1, r1w2, r1b2, r1w3, r1b3, l0, l1, l2, timeg,
        h1, v1, feats);
    pass2_kernel<<<B_*N_, 256, 0, stream>>>(rad, Y1, maskf,
        r2w0, r2b0, r2w1, r2b1, r2w2, r2b2, r2w3, r2b3, mix2, h1, v1, feats);
    final_kernel<<<B_*N_, 256, 0, stream>>>(feats, mw0, mb0, mw1, mb1, mw2, mb2,
        (float*)d_out);
}

// Round 2
// 504.643 us; speedup vs baseline: 1.7324x; 1.7324x over previous
//
#include <hip/hip_runtime.h>
#include <math.h>

#define B_ 32
#define N_ 64
#define K_ 128
#define NPAIR (B_*N_*N_)

__device__ __forceinline__ float silu_f(float x) {
    return x / (1.0f + expf(-x));
}
__device__ __forceinline__ float4 ld4(const float* p) { return *(const float4*)p; }

// ---------------------------------------------------------------------------
// Kernel 1: per-pair geometry -> rad[8], Y1[3], Y2[5], maskf
// ---------------------------------------------------------------------------
__global__ __launch_bounds__(256) void geom_kernel(
    const float* __restrict__ pos, const float* __restrict__ cell,
    float* __restrict__ rad, float* __restrict__ Y1, float* __restrict__ Y2,
    float* __restrict__ maskf)
{
    int p = blockIdx.x * 256 + threadIdx.x;
    if (p >= NPAIR) return;
    int b = p >> 12;
    int ij = p & 4095;
    int i = ij >> 6, j = ij & 63;
    const float* pi = pos + (size_t)(b*N_ + i)*3;
    const float* pj = pos + (size_t)(b*N_ + j)*3;
    float d0 = pi[0]-pj[0], d1 = pi[1]-pj[1], d2 = pi[2]-pj[2];
    d0 -= rintf(d0); d1 -= rintf(d1); d2 -= rintf(d2);
    const float* C = cell + b*9;
    float dc0 = d0*C[0] + d1*C[3] + d2*C[6];
    float dc1 = d0*C[1] + d1*C[4] + d2*C[7];
    float dc2 = d0*C[2] + d1*C[5] + d2*C[8];
    float r2 = fmaxf(dc0*dc0 + dc1*dc1 + dc2*dc2, 1e-12f);
    float r = sqrtf(r2);
    bool m = (r < 5.0f) && (i != j);
    float mf = m ? 1.0f : 0.0f;
    float rs = m ? r : 1.0f;
    float inv_rs = 1.0f / rs;
    float x = dc0*inv_rs*mf, y = dc1*inv_rs*mf, z = dc2*inv_rs*mf;
    float u = r * 0.2f;
    float u2 = u*u, u4 = u2*u2, u5 = u4*u;
    float fc = 1.0f - 21.0f*u5 + 35.0f*u5*u - 15.0f*u5*u2;
    fc = (u < 1.0f) ? fc : 0.0f;
    float pref = 0.6324555320336759f * inv_rs * (fc * mf);
    float w = 0.6283185307179586f * rs;
    #pragma unroll
    for (int n = 1; n <= 8; n++)
        rad[(size_t)p*8 + (n-1)] = pref * sinf((float)n * w);
    const float s3  = 1.7320508075688772f;
    const float s5  = 2.23606797749979f;
    const float s15 = 3.872983346207417f;
    float* y1 = Y1 + (size_t)p*3;
    y1[0] = s3*x; y1[1] = s3*y; y1[2] = s3*z;
    float* y2 = Y2 + (size_t)p*5;
    y2[0] = s15*x*y;
    y2[1] = s15*y*z;
    y2[2] = 0.5f*s5*(3.0f*z*z - 1.0f);
    y2[3] = s15*x*z;
    y2[4] = 0.5f*s15*(x*x - y*y);
    maskf[p] = mf;
}

// ---------------------------------------------------------------------------
// Register-tiled 64x64 MLP layer: src (LDS, transposed [k][68]) @ w (global
// [k][64]) + bias -> silu -> dst (LDS, transposed [h][68]).
// 16x16 thread grid, 4x4 tile per thread. Per k: 1 ds_read_b128 (broadcast,
// conflict-free) + 1 coalesced 256B global load + 16 FMA.
// ---------------------------------------------------------------------------
__device__ __forceinline__ void mlp_layer64(
    const float* __restrict__ src, const float* __restrict__ w,
    const float* __restrict__ bias, float* __restrict__ dst, int tj, int th)
{
    float acc[4][4];
    float4 bv = ld4(&bias[4*th]);
    #pragma unroll
    for (int jj = 0; jj < 4; jj++) {
        acc[jj][0] = bv.x; acc[jj][1] = bv.y; acc[jj][2] = bv.z; acc[jj][3] = bv.w;
    }
    #pragma unroll 8
    for (int k = 0; k < 64; k++) {
        float4 av = ld4(&src[k*68 + 4*tj]);
        float4 wv = ld4(&w[k*64 + 4*th]);
        float af[4] = {av.x, av.y, av.z, av.w};
        float wf[4] = {wv.x, wv.y, wv.z, wv.w};
        #pragma unroll
        for (int jj = 0; jj < 4; jj++)
            #pragma unroll
            for (int hh = 0; hh < 4; hh++)
                acc[jj][hh] += af[jj] * wf[hh];
    }
    #pragma unroll
    for (int hh = 0; hh < 4; hh++) {
        float4 o;
        o.x = silu_f(acc[0][hh]); o.y = silu_f(acc[1][hh]);
        o.z = silu_f(acc[2][hh]); o.w = silu_f(acc[3][hh]);
        *(float4*)&dst[(4*th + hh)*68 + 4*tj] = o;
    }
}

// layer 0: K=8 variant
__device__ __forceinline__ void mlp_layer0(
    const float* __restrict__ radT, const float* __restrict__ w,
    const float* __restrict__ bias, float* __restrict__ dst, int tj, int th)
{
    float acc[4][4];
    float4 bv = ld4(&bias[4*th]);
    #pragma unroll
    for (int jj = 0; jj < 4; jj++) {
        acc[jj][0] = bv.x; acc[jj][1] = bv.y; acc[jj][2] = bv.z; acc[jj][3] = bv.w;
    }
    #pragma unroll
    for (int k = 0; k < 8; k++) {
        float4 av = ld4(&radT[k*68 + 4*tj]);
        float4 wv = ld4(&w[k*64 + 4*th]);
        float af[4] = {av.x, av.y, av.z, av.w};
        float wf[4] = {wv.x, wv.y, wv.z, wv.w};
        #pragma unroll
        for (int jj = 0; jj < 4; jj++)
            #pragma unroll
            for (int hh = 0; hh < 4; hh++)
                acc[jj][hh] += af[jj] * wf[hh];
    }
    #pragma unroll
    for (int hh = 0; hh < 4; hh++) {
        float4 o;
        o.x = silu_f(acc[0][hh]); o.y = silu_f(acc[1][hh]);
        o.z = silu_f(acc[2][hh]); o.w = silu_f(acc[3][hh]);
        *(float4*)&dst[(4*th + hh)*68 + 4*tj] = o;
    }
}

// ---------------------------------------------------------------------------
// Kernel 2 (pass 1): one block per node. Radial MLP1 (register-tiled, hcT in
// LDS transposed), factored last layer via G[m,h], then s1/v1/h1/feats.
// ---------------------------------------------------------------------------
__global__ __launch_bounds__(256) void pass1_kernel(
    const float* __restrict__ rad, const float* __restrict__ Y1g,
    const float* __restrict__ Y2g, const float* __restrict__ maskg,
    const float* __restrict__ wemb,
    const float* __restrict__ w0, const float* __restrict__ b0,
    const float* __restrict__ w1, const float* __restrict__ b1,
    const float* __restrict__ w2, const float* __restrict__ b2,
    const float* __restrict__ w3, const float* __restrict__ b3,
    const float* __restrict__ l0, const float* __restrict__ l1,
    const float* __restrict__ l2, const float* __restrict__ timeg,
    float* __restrict__ h1g, float* __restrict__ v1g, float* __restrict__ featsg)
{
    __shared__ float radT[8*68];
    __shared__ float actA[64*68];
    __shared__ float actB[64*68];
    __shared__ float Ym[9*64];
    __shared__ float G[9*64];
    __shared__ float SY[9];
    __shared__ float msg[9*128];
    __shared__ float q[128];
    int t = threadIdx.x;
    int tj = t >> 4, th = t & 15;
    int node = blockIdx.x;
    int b = node >> 6;
    size_t pbase = (size_t)node * 64;

    for (int idx = t; idx < 512; idx += 256) {
        int j = idx >> 3, c = idx & 7;
        radT[c*68 + j] = rad[pbase*8 + idx];
    }
    if (t < 64) {
        int j = t;
        float mf = maskg[pbase + j];
        Ym[j] = mf;
        #pragma unroll
        for (int m = 0; m < 3; m++) Ym[(1+m)*64 + j] = Y1g[(pbase+j)*3 + m] * mf;
        #pragma unroll
        for (int m = 0; m < 5; m++) Ym[(4+m)*64 + j] = Y2g[(pbase+j)*5 + m] * mf;
    }
    __syncthreads();

    mlp_layer0(radT, w0, b0, actA, tj, th);
    __syncthreads();
    mlp_layer64(actA, w1, b1, actB, tj, th);
    __syncthreads();
    mlp_layer64(actB, w2, b2, actA, tj, th);   // hcT -> actA [h][68]
    __syncthreads();

    if (t < 9) {
        float acc = 0.f;
        for (int j = 0; j < 64; j++) acc += Ym[t*64 + j];
        SY[t] = acc;
    }
    for (int idx = t; idx < 576; idx += 256) {
        int m = idx >> 6, h = idx & 63;
        float acc = 0.f;
        #pragma unroll
        for (int j4 = 0; j4 < 16; j4++) {
            float4 yv = ld4(&Ym[m*64 + 4*j4]);
            float4 av = ld4(&actA[h*68 + 4*j4]);
            acc += yv.x*av.x + yv.y*av.y + yv.z*av.z + yv.w*av.w;
        }
        G[m*64 + h] = acc;
    }
    __syncthreads();

    for (int idx = t; idx < 1152; idx += 256) {
        int m = idx >> 7, k = idx & 127;
        int c = (m == 0) ? 0 : ((m < 4) ? 1 : 2);
        int col = c*128 + k;
        float acc = SY[m] * b3[col];
        #pragma unroll 8
        for (int h = 0; h < 64; h++) acc += G[m*64 + h] * w3[h*384 + col];
        msg[m*128 + k] = acc * wemb[k] * 0.0625f;
    }
    __syncthreads();

    if (t < 128) {
        int k = t;
        float acc = 0.f;
        #pragma unroll
        for (int m = 4; m < 9; m++) { float v = msg[m*128 + k]; acc += v*v; }
        q[k] = acc;
    }
    __syncthreads();

    for (int idx = t; idx < 512; idx += 256) {
        if (idx < 128) {
            int c = idx;
            float acc = 0.f;
            for (int k = 0; k < 128; k++)
                acc += msg[k]*l0[k*128 + c] + q[k]*l2[k*128 + c];
            featsg[(size_t)node*641 + c] = acc;
            h1g[(size_t)node*128 + c] = silu_f(acc);
        } else {
            int vi = idx - 128;
            int m = vi >> 7, c = vi & 127;
            float acc = 0.f;
            for (int k = 0; k < 128; k++) acc += msg[(1+m)*128 + k]*l1[k*128 + c];
            v1g[(size_t)node*384 + m*128 + c] = acc;
            featsg[(size_t)node*641 + 128 + m*128 + c] = acc;
        }
    }
    if (t == 0) featsg[(size_t)node*641 + 640] = timeg[b];
}

// ---------------------------------------------------------------------------
// Kernel 3 (pass 2): one block per node. Radial MLP2 register-tiled; we2
// never materialized: both channels' 4x4 tiles in registers per 64-col chunk,
// combined with h1/inv, LDS-atomicAdd into msgab; s2 = msgab@mix2/16.
// ---------------------------------------------------------------------------
__global__ __launch_bounds__(256) void pass2_kernel(
    const float* __restrict__ rad, const float* __restrict__ Y1g,
    const float* __restrict__ maskg,
    const float* __restrict__ w0, const float* __restrict__ b0,
    const float* __restrict__ w1, const float* __restrict__ b1,
    const float* __restrict__ w2, const float* __restrict__ b2,
    const float* __restrict__ w3, const float* __restrict__ b3,
    const float* __restrict__ mix2,
    const float* __restrict__ h1g, const float* __restrict__ v1g,
    float* __restrict__ featsg)
{
    __shared__ float radT[8*68];
    __shared__ float actA[64*68];
    __shared__ float actB[64*68];
    __shared__ float Y1s[64*4];
    __shared__ float mask_s[64];
    __shared__ float msgab[128];
    int t = threadIdx.x;
    int tj = t >> 4, th = t & 15;
    int node = blockIdx.x;
    int b = node >> 6;
    size_t pbase = (size_t)node * 64;

    for (int idx = t; idx < 512; idx += 256) {
        int j = idx >> 3, c = idx & 7;
        radT[c*68 + j] = rad[pbase*8 + idx];
    }
    if (t < 64) {
        mask_s[t] = maskg[pbase + t];
        #pragma unroll
        for (int m = 0; m < 3; m++) Y1s[t*4 + m] = Y1g[(pbase+t)*3 + m];
    }
    if (t < 128) msgab[t] = 0.f;
    __syncthreads();

    mlp_layer0(radT, w0, b0, actA, tj, th);
    __syncthreads();
    mlp_layer64(actA, w1, b1, actB, tj, th);
    __syncthreads();
    mlp_layer64(actB, w2, b2, actA, tj, th);   // hcT -> actA
    __syncthreads();

    // we2 chunks: chunk c covers ch0 cols [64c,64c+64) and ch1 same range
    for (int c = 0; c < 2; c++) {
        int kcol = c*64 + 4*th;
        float a0[4][4], a1[4][4];
        float4 b3v0 = ld4(&b3[kcol]);
        float4 b3v1 = ld4(&b3[128 + kcol]);
        #pragma unroll
        for (int jj = 0; jj < 4; jj++) {
            a0[jj][0]=b3v0.x; a0[jj][1]=b3v0.y; a0[jj][2]=b3v0.z; a0[jj][3]=b3v0.w;
            a1[jj][0]=b3v1.x; a1[jj][1]=b3v1.y; a1[jj][2]=b3v1.z; a1[jj][3]=b3v1.w;
        }
        #pragma unroll 8
        for (int h = 0; h < 64; h++) {
            float4 av = ld4(&actA[h*68 + 4*tj]);
            float4 w0v = ld4(&w3[h*256 + kcol]);
            float4 w1v = ld4(&w3[h*256 + 128 + kcol]);
            float af[4] = {av.x, av.y, av.z, av.w};
            float wf0[4] = {w0v.x, w0v.y, w0v.z, w0v.w};
            float wf1[4] = {w1v.x, w1v.y, w1v.z, w1v.w};
            #pragma unroll
            for (int jj = 0; jj < 4; jj++)
                #pragma unroll
                for (int qq = 0; qq < 4; qq++) {
                    a0[jj][qq] += af[jj]*wf0[qq];
                    a1[jj][qq] += af[jj]*wf1[qq];
                }
        }
        float pa[4] = {0.f, 0.f, 0.f, 0.f};
        #pragma unroll
        for (int jj = 0; jj < 4; jj++) {
            int j = 4*tj + jj;
            float mf = mask_s[j];
            float4 hv = ld4(&h1g[((size_t)b*64 + j)*128 + kcol]);
            const float* vbase = &v1g[((size_t)b*64 + j)*384 + kcol];
            float4 vx = ld4(vbase);
            float4 vy = ld4(vbase + 128);
            float4 vz = ld4(vbase + 256);
            float yx = Y1s[j*4+0], yy = Y1s[j*4+1], yz = Y1s[j*4+2];
            float hvf[4] = {hv.x, hv.y, hv.z, hv.w};
            float ivf[4] = {yx*vx.x + yy*vy.x + yz*vz.x,
                            yx*vx.y + yy*vy.y + yz*vz.y,
                            yx*vx.z + yy*vy.z + yz*vz.z,
                            yx*vx.w + yy*vy.w + yz*vz.w};
            #pragma unroll
            for (int qq = 0; qq < 4; qq++)
                pa[qq] += mf * (a0[jj][qq]*hvf[qq] + a1[jj][qq]*ivf[qq]);
        }
        #pragma unroll
        for (int qq = 0; qq < 4; qq++)
            atomicAdd(&msgab[kcol + qq], pa[qq]);
    }
    __syncthreads();

    if (t < 128) {
        int c = t;
        float acc = 0.f;
        for (int k = 0; k < 128; k++) acc += msgab[k] * mix2[k*128 + c];
        featsg[(size_t)node*641 + 512 + c] = acc * 0.0625f;
    }
}

// ---------------------------------------------------------------------------
// Tiled fp32 GEMM: C[M,512] = act(A[M,K](lda) @ W[K,512] + bias), 64x64 tile,
// BK=32, 4x4 register tile/thread. relu flag compile-time via template-ish int.
// ---------------------------------------------------------------------------
__global__ __launch_bounds__(256) void gemm_relu_kernel(
    const float* __restrict__ A, int lda, int K,
    const float* __restrict__ W, const float* __restrict__ bias,
    float* __restrict__ C)
{
    __shared__ float At[32*68];
    __shared__ float Wt[32*68];
    int t = threadIdx.x;
    int tj = t >> 4, th = t & 15;
    int m0 = blockIdx.x * 64, h0 = blockIdx.y * 64;
    float acc[4][4];
    #pragma unroll
    for (int jj = 0; jj < 4; jj++)
        #pragma unroll
        for (int hh = 0; hh < 4; hh++) acc[jj][hh] = 0.f;

    int nch = (K + 31) / 32;
    for (int ch = 0; ch < nch; ch++) {
        int k0 = ch * 32;
        {   // stage A transposed (scalar loads: lda may be odd)
            int j = t >> 2, kb = (t & 3) * 8;
            const float* arow = A + (size_t)(m0 + j) * lda + k0 + kb;
            #pragma unroll
            for (int r = 0; r < 8; r++) {
                int k = k0 + kb + r;
                At[(kb + r)*68 + j] = (k < K) ? arow[r] : 0.f;
            }
        }
        {   // stage W natural
            int kk = t >> 3, hh = (t & 7) * 8;
            int k = k0 + kk;
            if (k < K) {
                float4 wv0 = ld4(&W[(size_t)k*512 + h0 + hh]);
                float4 wv1 = ld4(&W[(size_t)k*512 + h0 + hh + 4]);
                *(float4*)&Wt[kk*68 + hh] = wv0;
                *(float4*)&Wt[kk*68 + hh + 4] = wv1;
            } else {
                float4 z = {0.f, 0.f, 0.f, 0.f};
                *(float4*)&Wt[kk*68 + hh] = z;
                *(float4*)&Wt[kk*68 + hh + 4] = z;
            }
        }
        __syncthreads();
        #pragma unroll 8
        for (int kk = 0; kk < 32; kk++) {
            float4 av = ld4(&At[kk*68 + 4*tj]);
            float4 wv = ld4(&Wt[kk*68 + 4*th]);
            float af[4] = {av.x, av.y, av.z, av.w};
            float wf[4] = {wv.x, wv.y, wv.z, wv.w};
            #pragma unroll
            for (int jj = 0; jj < 4; jj++)
                #pragma unroll
                for (int hh = 0; hh < 4; hh++)
                    acc[jj][hh] += af[jj]*wf[hh];
        }
        __syncthreads();
    }
    float4 bv = ld4(&bias[h0 + 4*th]);
    float bf[4] = {bv.x, bv.y, bv.z, bv.w};
    #pragma unroll
    for (int jj = 0; jj < 4; jj++) {
        float4 o;
        o.x = fmaxf(acc[jj][0] + bf[0], 0.f);
        o.y = fmaxf(acc[jj][1] + bf[1], 0.f);
        o.z = fmaxf(acc[jj][2] + bf[2], 0.f);
        o.w = fmaxf(acc[jj][3] + bf[3], 0.f);
        *(float4*)&C[(size_t)(m0 + 4*tj + jj)*512 + h0 + 4*th] = o;
    }
}

// ---------------------------------------------------------------------------
// Final layer: out[node,3] = H[node,512] @ w2[512,3] + b2. One wave per node.
// ---------------------------------------------------------------------------
__global__ __launch_bounds__(64) void final3_kernel(
    const float* __restrict__ H, const float* __restrict__ w2,
    const float* __restrict__ b2, float* __restrict__ out)
{
    int node = blockIdx.x, lane = threadIdx.x;
    float a0 = 0.f, a1 = 0.f, a2 = 0.f;
    #pragma unroll
    for (int r = 0; r < 8; r++) {
        int k = r*64 + lane;
        float h = H[(size_t)node*512 + k];
        a0 += h * w2[k*3 + 0];
        a1 += h * w2[k*3 + 1];
        a2 += h * w2[k*3 + 2];
    }
    #pragma unroll
    for (int off = 32; off > 0; off >>= 1) {
        a0 += __shfl_down(a0, off);
        a1 += __shfl_down(a1, off);
        a2 += __shfl_down(a2, off);
    }
    if (lane == 0) {
        out[(size_t)node*3 + 0] = a0 + b2[0];
        out[(size_t)node*3 + 1] = a1 + b2[1];
        out[(size_t)node*3 + 2] = a2 + b2[2];
    }
}

extern "C" void kernel_launch(void* const* d_in, const int* in_sizes, int n_in,
                              void* d_out, int out_size, void* d_ws, size_t ws_size,
                              hipStream_t stream) {
    const float* pos   = (const float*)d_in[0];
    const float* timeg = (const float*)d_in[1];
    const float* cell  = (const float*)d_in[2];
    const float* wemb  = (const float*)d_in[3];
    const float* r1w0  = (const float*)d_in[4];
    const float* r1b0  = (const float*)d_in[5];
    const float* r1w1  = (const float*)d_in[6];
    const float* r1b1  = (const float*)d_in[7];
    const float* r1w2  = (const float*)d_in[8];
    const float* r1b2  = (const float*)d_in[9];
    const float* r1w3  = (const float*)d_in[10];
    const float* r1b3  = (const float*)d_in[11];
    const float* l0    = (const float*)d_in[12];
    const float* l1    = (const float*)d_in[13];
    const float* l2    = (const float*)d_in[14];
    const float* r2w0  = (const float*)d_in[15];
    const float* r2b0  = (const float*)d_in[16];
    const float* r2w1  = (const float*)d_in[17];
    const float* r2b1  = (const float*)d_in[18];
    const float* r2w2  = (const float*)d_in[19];
    const float* r2b2  = (const float*)d_in[20];
    const float* r2w3  = (const float*)d_in[21];
    const float* r2b3  = (const float*)d_in[22];
    const float* mix2  = (const float*)d_in[23];
    const float* mw0   = (const float*)d_in[24];
    const float* mb0   = (const float*)d_in[25];
    const float* mw1   = (const float*)d_in[26];
    const float* mb1   = (const float*)d_in[27];
    const float* mw2   = (const float*)d_in[28];
    const float* mb2   = (const float*)d_in[29];

    float* ws    = (float*)d_ws;
    float* rad   = ws;                                  // NPAIR*8  = 1048576 f
    float* Y1    = rad   + (size_t)NPAIR*8;             // NPAIR*3
    float* Y2    = Y1    + (size_t)NPAIR*3;             // NPAIR*5
    float* maskf = Y2    + (size_t)NPAIR*5;             // NPAIR
    float* h1    = maskf + (size_t)NPAIR;               // B*N*K
    float* v1    = h1    + (size_t)B_*N_*K_;            // B*N*3*K
    float* feats = v1    + (size_t)B_*N_*3*K_;          // B*N*641
    // final-MLP scratch ALIASES dead geometry buffers (rad / Y1+Y2+mask):
    // h0b = 2048*512 = 1048576 floats == rad region exactly;
    // h1b = 1048576 floats <= Y1+Y2+mask region (1179648 floats).
    float* h0b = rad;
    float* h1b = Y1;

    geom_kernel<<<NPAIR/256, 256, 0, stream>>>(pos, cell, rad, Y1, Y2, maskf);
    pass1_kernel<<<B_*N_, 256, 0, stream>>>(rad, Y1, Y2, maskf, wemb,
        r1w0, r1b0, r1w1, r1b1, r1w2, r1b2, r1w3, r1b3, l0, l1, l2, timeg,
        h1, v1, feats);
    pass2_kernel<<<B_*N_, 256, 0, stream>>>(rad, Y1, maskf,
        r2w0, r2b0, r2w1, r2b1, r2w2, r2b2, r2w3, r2b3, mix2, h1, v1, feats);
    dim3 g1(B_*N_/64, 8);
    gemm_relu_kernel<<<g1, 256, 0, stream>>>(feats, 641, 641, mw0, mb0, h0b);
    gemm_relu_kernel<<<g1, 256, 0, stream>>>(h0b, 512, 512, mw1, mb1, h1b);
    final3_kernel<<<B_*N_, 64, 0, stream>>>(h1b, mw2, mb2, (float*)d_out);
}

// Round 3
// 286.041 us; speedup vs baseline: 3.0563x; 1.7642x over previous
//
#include <hip/hip_runtime.h>
#include <math.h>

#define B_ 32
#define N_ 64
#define K_ 128
#define NPAIR (B_*N_*N_)

typedef __attribute__((ext_vector_type(8))) short short8;
typedef __attribute__((ext_vector_type(8))) __bf16 bf16x8;
typedef __attribute__((ext_vector_type(4))) float floatx4;

__device__ __forceinline__ float silu_f(float x) {
    return x / (1.0f + expf(-x));
}
__device__ __forceinline__ float4 ld4(const float* p) { return *(const float4*)p; }

__device__ __forceinline__ short f2bf(float x) {
    union { float f; unsigned u; } v; v.f = x;
    unsigned r = (v.u + 0x7FFFu + ((v.u >> 16) & 1u)) >> 16;
    return (short)r;
}
__device__ __forceinline__ float bf2f(short s) {
    union { unsigned u; float f; } v;
    v.u = ((unsigned)(unsigned short)s) << 16;
    return v.f;
}
__device__ __forceinline__ bf16x8 ld_frag(const short* p) {
    short8 r = *(const short8*)p;
    return __builtin_bit_cast(bf16x8, r);
}

// ---------------------------------------------------------------------------
// Kernel 0: weight prep -> bf16 transposed layouts (B-operand: BT[n][k])
// sections (short offsets): r1w1T 0..4096, r1w2T ..8192, r2w1T ..12288,
// r2w2T ..16384, r2w3T ..32768 [256][64], wT0 ..393216 [512][704] (zero-pad
// k>=641), wT1 ..655360 [512][512]
// ---------------------------------------------------------------------------
__global__ __launch_bounds__(256) void prep_kernel(
    const float* __restrict__ r1w1, const float* __restrict__ r1w2,
    const float* __restrict__ r2w1, const float* __restrict__ r2w2,
    const float* __restrict__ r2w3, const float* __restrict__ mw0,
    const float* __restrict__ mw1, short* __restrict__ dst)
{
    int idx = blockIdx.x * 256 + threadIdx.x;
    if (idx >= 655360) return;
    short v;
    if (idx < 4096) {
        int h = idx >> 6, k = idx & 63; v = f2bf(r1w1[k*64 + h]);
    } else if (idx < 8192) {
        int i = idx - 4096; int h = i >> 6, k = i & 63; v = f2bf(r1w2[k*64 + h]);
    } else if (idx < 12288) {
        int i = idx - 8192; int h = i >> 6, k = i & 63; v = f2bf(r2w1[k*64 + h]);
    } else if (idx < 16384) {
        int i = idx - 12288; int h = i >> 6, k = i & 63; v = f2bf(r2w2[k*64 + h]);
    } else if (idx < 32768) {
        int i = idx - 16384; int col = i >> 6, h = i & 63; v = f2bf(r2w3[h*256 + col]);
    } else if (idx < 393216) {
        int i = idx - 32768; int n = i / 704, k = i - n*704;
        v = (k < 641) ? f2bf(mw0[(size_t)k*512 + n]) : (short)0;
    } else {
        int i = idx - 393216; int n = i >> 9, k = i & 511;
        v = f2bf(mw1[(size_t)k*512 + n]);
    }
    dst[idx] = v;
}

// ---------------------------------------------------------------------------
// Kernel 1: per-pair geometry -> rad[8], Y1[3], Y2[5], maskf  (fp32)
// ---------------------------------------------------------------------------
__global__ __launch_bounds__(256) void geom_kernel(
    const float* __restrict__ pos, const float* __restrict__ cell,
    float* __restrict__ rad, float* __restrict__ Y1, float* __restrict__ Y2,
    float* __restrict__ maskf)
{
    int p = blockIdx.x * 256 + threadIdx.x;
    if (p >= NPAIR) return;
    int b = p >> 12;
    int ij = p & 4095;
    int i = ij >> 6, j = ij & 63;
    const float* pi = pos + (size_t)(b*N_ + i)*3;
    const float* pj = pos + (size_t)(b*N_ + j)*3;
    float d0 = pi[0]-pj[0], d1 = pi[1]-pj[1], d2 = pi[2]-pj[2];
    d0 -= rintf(d0); d1 -= rintf(d1); d2 -= rintf(d2);
    const float* C = cell + b*9;
    float dc0 = d0*C[0] + d1*C[3] + d2*C[6];
    float dc1 = d0*C[1] + d1*C[4] + d2*C[7];
    float dc2 = d0*C[2] + d1*C[5] + d2*C[8];
    float r2 = fmaxf(dc0*dc0 + dc1*dc1 + dc2*dc2, 1e-12f);
    float r = sqrtf(r2);
    bool m = (r < 5.0f) && (i != j);
    float mf = m ? 1.0f : 0.0f;
    float rs = m ? r : 1.0f;
    float inv_rs = 1.0f / rs;
    float x = dc0*inv_rs*mf, y = dc1*inv_rs*mf, z = dc2*inv_rs*mf;
    float u = r * 0.2f;
    float u2 = u*u, u4 = u2*u2, u5 = u4*u;
    float fc = 1.0f - 21.0f*u5 + 35.0f*u5*u - 15.0f*u5*u2;
    fc = (u < 1.0f) ? fc : 0.0f;
    float pref = 0.6324555320336759f * inv_rs * (fc * mf);
    float w = 0.6283185307179586f * rs;
    #pragma unroll
    for (int n = 1; n <= 8; n++)
        rad[(size_t)p*8 + (n-1)] = pref * sinf((float)n * w);
    const float s3  = 1.7320508075688772f;
    const float s5  = 2.23606797749979f;
    const float s15 = 3.872983346207417f;
    float* y1 = Y1 + (size_t)p*3;
    y1[0] = s3*x; y1[1] = s3*y; y1[2] = s3*z;
    float* y2 = Y2 + (size_t)p*5;
    y2[0] = s15*x*y;
    y2[1] = s15*y*z;
    y2[2] = 0.5f*s5*(3.0f*z*z - 1.0f);
    y2[3] = s15*x*z;
    y2[4] = 0.5f*s15*(x*x - y*y);
    maskf[p] = mf;
}

// ---------------------------------------------------------------------------
// Shared MFMA MLP layer: act[64][72]bf16 (LDS) @ WT[64n][64k]bf16 (global)
// -> silu -> dst[64][72]bf16. Wave w owns row-stripe [16w,16w+16).
// ---------------------------------------------------------------------------
__device__ __forceinline__ void mfma_layer(
    const short* __restrict__ src, const short* __restrict__ WT,
    const float* __restrict__ bias, short* __restrict__ dst,
    int wv, int qd, int nn)
{
    floatx4 acc[4];
    #pragma unroll
    for (int tt = 0; tt < 4; tt++) acc[tt] = (floatx4){0.f, 0.f, 0.f, 0.f};
    #pragma unroll
    for (int ks = 0; ks < 64; ks += 32) {
        bf16x8 a = ld_frag(&src[(wv*16 + nn)*72 + ks + qd*8]);
        #pragma unroll
        for (int tt = 0; tt < 4; tt++) {
            bf16x8 b = ld_frag(&WT[(tt*16 + nn)*64 + ks + qd*8]);
            acc[tt] = __builtin_amdgcn_mfma_f32_16x16x32_bf16(a, b, acc[tt], 0, 0, 0);
        }
    }
    #pragma unroll
    for (int tt = 0; tt < 4; tt++) {
        int col = tt*16 + nn;
        float bv = bias[col];
        #pragma unroll
        for (int i = 0; i < 4; i++) {
            int row = wv*16 + qd*4 + i;
            dst[row*72 + col] = f2bf(silu_f(acc[tt][i] + bv));
        }
    }
}

// ---------------------------------------------------------------------------
// Kernel 2 (pass 1): one block per node. L0 fp32 -> bf16; L1/L2 MFMA;
// factored last layer (G, msg) fp32; s1/v1/h1 fp32; feats written bf16.
// ---------------------------------------------------------------------------
__global__ __launch_bounds__(256) void pass1_kernel(
    const float* __restrict__ rad, const float* __restrict__ Y1g,
    const float* __restrict__ Y2g, const float* __restrict__ maskg,
    const float* __restrict__ wemb,
    const float* __restrict__ w0, const float* __restrict__ b0,
    const short* __restrict__ w1T, const float* __restrict__ b1,
    const short* __restrict__ w2T, const float* __restrict__ b2,
    const float* __restrict__ w3, const float* __restrict__ b3,
    const float* __restrict__ l0, const float* __restrict__ l1,
    const float* __restrict__ l2, const float* __restrict__ timeg,
    float* __restrict__ h1g, float* __restrict__ v1g, short* __restrict__ featsb)
{
    __shared__ float rad_s[512];
    __shared__ short actA[64*72];
    __shared__ short actB[64*72];
    __shared__ float Ym[9*64];
    __shared__ float G[9*64];
    __shared__ float SY[9];
    __shared__ float msg[9*128];
    __shared__ float q_s[128];
    int t = threadIdx.x;
    int wv = t >> 6, lane = t & 63, qd = lane >> 4, nn = lane & 15;
    int node = blockIdx.x;
    int b = node >> 6;
    size_t pbase = (size_t)node * 64;

    for (int idx = t; idx < 512; idx += 256) rad_s[idx] = rad[pbase*8 + idx];
    if (t < 64) {
        int j = t;
        float mf = maskg[pbase + j];
        Ym[j] = mf;
        #pragma unroll
        for (int m = 0; m < 3; m++) Ym[(1+m)*64 + j] = Y1g[(pbase+j)*3 + m] * mf;
        #pragma unroll
        for (int m = 0; m < 5; m++) Ym[(4+m)*64 + j] = Y2g[(pbase+j)*5 + m] * mf;
    }
    __syncthreads();

    // layer 0 (K=8) in fp32 -> actA bf16
    for (int idx = t; idx < 4096; idx += 256) {
        int j = idx >> 6, h = idx & 63;
        float acc = b0[h];
        #pragma unroll
        for (int c = 0; c < 8; c++) acc += rad_s[j*8+c] * w0[c*64+h];
        actA[j*72 + h] = f2bf(silu_f(acc));
    }
    __syncthreads();
    mfma_layer(actA, w1T, b1, actB, wv, qd, nn);
    __syncthreads();
    mfma_layer(actB, w2T, b2, actA, wv, qd, nn);   // hc -> actA (bf16)
    __syncthreads();

    if (t < 9) {
        float acc = 0.f;
        for (int j = 0; j < 64; j++) acc += Ym[t*64 + j];
        SY[t] = acc;
    }
    for (int idx = t; idx < 576; idx += 256) {
        int m = idx >> 6, h = idx & 63;
        float acc = 0.f;
        #pragma unroll 8
        for (int j = 0; j < 64; j++) acc += Ym[m*64 + j] * bf2f(actA[j*72 + h]);
        G[m*64 + h] = acc;
    }
    __syncthreads();

    for (int idx = t; idx < 1152; idx += 256) {
        int m = idx >> 7, k = idx & 127;
        int c = (m == 0) ? 0 : ((m < 4) ? 1 : 2);
        int col = c*128 + k;
        float acc = SY[m] * b3[col];
        #pragma unroll 8
        for (int h = 0; h < 64; h++) acc += G[m*64 + h] * w3[h*384 + col];
        msg[m*128 + k] = acc * wemb[k] * 0.0625f;
    }
    __syncthreads();

    if (t < 128) {
        int k = t;
        float acc = 0.f;
        #pragma unroll
        for (int m = 4; m < 9; m++) { float v = msg[m*128 + k]; acc += v*v; }
        q_s[k] = acc;
    }
    __syncthreads();

    for (int idx = t; idx < 512; idx += 256) {
        if (idx < 128) {
            int c = idx;
            float acc = 0.f;
            for (int k = 0; k < 128; k++)
                acc += msg[k]*l0[k*128 + c] + q_s[k]*l2[k*128 + c];
            featsb[(size_t)node*704 + c] = f2bf(acc);     // s1
            h1g[(size_t)node*128 + c] = silu_f(acc);
        } else {
            int vi = idx - 128;
            int m = vi >> 7, c = vi & 127;
            float acc = 0.f;
            for (int k = 0; k < 128; k++) acc += msg[(1+m)*128 + k]*l1[k*128 + c];
            v1g[(size_t)node*384 + m*128 + c] = acc;
            featsb[(size_t)node*704 + 128 + m*128 + c] = f2bf(acc);
        }
    }
    if (t == 0) featsb[(size_t)node*704 + 640] = f2bf(timeg[b]);
    if (t < 63) featsb[(size_t)node*704 + 641 + t] = 0;   // zero K-pad
}

// ---------------------------------------------------------------------------
// Kernel 3 (pass 2): L0 fp32, L1/L2 MFMA, we2 via MFMA [64x64]@[64x256]
// (never materialized to global), combine with h1/inv, s2 = msgab@mix2/16.
// ---------------------------------------------------------------------------
__global__ __launch_bounds__(256) void pass2_kernel(
    const float* __restrict__ rad, const float* __restrict__ Y1g,
    const float* __restrict__ maskg,
    const float* __restrict__ w0, const float* __restrict__ b0,
    const short* __restrict__ w1T, const float* __restrict__ b1,
    const short* __restrict__ w2T, const float* __restrict__ b2,
    const short* __restrict__ w3T, const float* __restrict__ b3,
    const float* __restrict__ mix2,
    const float* __restrict__ h1g, const float* __restrict__ v1g,
    short* __restrict__ featsb)
{
    __shared__ float rad_s[512];
    __shared__ short actA[64*72];
    __shared__ short actB[64*72];
    __shared__ float Y1s[64*4];
    __shared__ float mask_s[64];
    __shared__ float msgab[128];
    int t = threadIdx.x;
    int wv = t >> 6, lane = t & 63, qd = lane >> 4, nn = lane & 15;
    int node = blockIdx.x;
    int b = node >> 6;
    size_t pbase = (size_t)node * 64;

    for (int idx = t; idx < 512; idx += 256) rad_s[idx] = rad[pbase*8 + idx];
    if (t < 64) {
        mask_s[t] = maskg[pbase + t];
        #pragma unroll
        for (int m = 0; m < 3; m++) Y1s[t*4 + m] = Y1g[(pbase+t)*3 + m];
    }
    if (t < 128) msgab[t] = 0.f;
    __syncthreads();

    for (int idx = t; idx < 4096; idx += 256) {
        int j = idx >> 6, h = idx & 63;
        float acc = b0[h];
        #pragma unroll
        for (int c = 0; c < 8; c++) acc += rad_s[j*8+c] * w0[c*64+h];
        actA[j*72 + h] = f2bf(silu_f(acc));
    }
    __syncthreads();
    mfma_layer(actA, w1T, b1, actB, wv, qd, nn);
    __syncthreads();
    mfma_layer(actB, w2T, b2, actA, wv, qd, nn);   // hc -> actA
    __syncthreads();

    // we2 = hc @ w3 : [64 rows][256 cols]; wave owns rows [16wv,16wv+16),
    // 4 groups of 4 n-tiles to bound VGPR.
    for (int g = 0; g < 4; g++) {
        floatx4 acc[4];
        #pragma unroll
        for (int tt = 0; tt < 4; tt++) acc[tt] = (floatx4){0.f, 0.f, 0.f, 0.f};
        #pragma unroll
        for (int ks = 0; ks < 64; ks += 32) {
            bf16x8 a = ld_frag(&actA[(wv*16 + nn)*72 + ks + qd*8]);
            #pragma unroll
            for (int tt = 0; tt < 4; tt++) {
                int col0 = g*64 + tt*16;
                bf16x8 bb = ld_frag(&w3T[(col0 + nn)*64 + ks + qd*8]);
                acc[tt] = __builtin_amdgcn_mfma_f32_16x16x32_bf16(a, bb, acc[tt], 0, 0, 0);
            }
        }
        #pragma unroll
        for (int tt = 0; tt < 4; tt++) {
            int col = g*64 + tt*16 + nn;
            float bias = b3[col];
            int k = col & 127;
            float p = 0.f;
            if (col < 128) {
                #pragma unroll
                for (int i = 0; i < 4; i++) {
                    int j = wv*16 + qd*4 + i;
                    float we = (acc[tt][i] + bias) * mask_s[j];
                    p += we * h1g[((size_t)b*64 + j)*128 + k];
                }
            } else {
                #pragma unroll
                for (int i = 0; i < 4; i++) {
                    int j = wv*16 + qd*4 + i;
                    float we = (acc[tt][i] + bias) * mask_s[j];
                    const float* vb = &v1g[((size_t)b*64 + j)*384 + k];
                    float inv = Y1s[j*4+0]*vb[0] + Y1s[j*4+1]*vb[128] + Y1s[j*4+2]*vb[256];
                    p += we * inv;
                }
            }
            p += __shfl_xor(p, 16);
            p += __shfl_xor(p, 32);
            if (qd == 0) atomicAdd(&msgab[k], p);
        }
    }
    __syncthreads();

    if (t < 128) {
        int c = t;
        float acc = 0.f;
        for (int k = 0; k < 128; k++) acc += msgab[k] * mix2[k*128 + c];
        featsb[(size_t)node*704 + 512 + c] = f2bf(acc * 0.0625f);   // s2
    }
}

// ---------------------------------------------------------------------------
// Kernel 4: bf16 MFMA GEMM, C[M][ldo] = relu(A[M][lda] @ WT^T + bias), bf16 out.
// 64x64 tile per block, K multiple of 64. BT layout [n][k].
// ---------------------------------------------------------------------------
__global__ __launch_bounds__(256) void gemm_mfma_kernel(
    const short* __restrict__ A, int lda,
    const short* __restrict__ BT, int ldb, int K,
    const float* __restrict__ bias, short* __restrict__ Cout, int ldo)
{
    __shared__ short As[64*72];
    __shared__ short Bs[64*72];
    int t = threadIdx.x;
    int wv = t >> 6, lane = t & 63, qd = lane >> 4, nn = lane & 15;
    int m0 = blockIdx.x * 64, n0 = blockIdx.y * 64;
    floatx4 acc[4];
    #pragma unroll
    for (int tt = 0; tt < 4; tt++) acc[tt] = (floatx4){0.f, 0.f, 0.f, 0.f};

    for (int kc = 0; kc < K; kc += 64) {
        for (int s = t; s < 512; s += 256) {
            int j = s >> 3, kk = (s & 7) * 8;
            *(uint4*)&As[j*72 + kk] = *(const uint4*)&A[(size_t)(m0 + j)*lda + kc + kk];
            *(uint4*)&Bs[j*72 + kk] = *(const uint4*)&BT[(size_t)(n0 + j)*ldb + kc + kk];
        }
        __syncthreads();
        #pragma unroll
        for (int ks = 0; ks < 64; ks += 32) {
            bf16x8 a = ld_frag(&As[(wv*16 + nn)*72 + ks + qd*8]);
            #pragma unroll
            for (int tt = 0; tt < 4; tt++) {
                bf16x8 bb = ld_frag(&Bs[(tt*16 + nn)*72 + ks + qd*8]);
                acc[tt] = __builtin_amdgcn_mfma_f32_16x16x32_bf16(a, bb, acc[tt], 0, 0, 0);
            }
        }
        __syncthreads();
    }
    #pragma unroll
    for (int tt = 0; tt < 4; tt++) {
        int n = n0 + tt*16 + nn;
        float bv = bias[n];
        #pragma unroll
        for (int i = 0; i < 4; i++) {
            int m = m0 + wv*16 + qd*4 + i;
            Cout[(size_t)m*ldo + n] = f2bf(fmaxf(acc[tt][i] + bv, 0.f));
        }
    }
}

// ---------------------------------------------------------------------------
// Kernel 5: out[node,3] = H(bf16)[node,512] @ w2[512,3] + b2. One wave/node.
// ---------------------------------------------------------------------------
__global__ __launch_bounds__(64) void final3_kernel(
    const short* __restrict__ H, const float* __restrict__ w2,
    const float* __restrict__ b2, float* __restrict__ out)
{
    int node = blockIdx.x, lane = threadIdx.x;
    float a0 = 0.f, a1 = 0.f, a2 = 0.f;
    #pragma unroll
    for (int r = 0; r < 8; r++) {
        int k = r*64 + lane;
        float h = bf2f(H[(size_t)node*512 + k]);
        a0 += h * w2[k*3 + 0];
        a1 += h * w2[k*3 + 1];
        a2 += h * w2[k*3 + 2];
    }
    #pragma unroll
    for (int off = 32; off > 0; off >>= 1) {
        a0 += __shfl_down(a0, off);
        a1 += __shfl_down(a1, off);
        a2 += __shfl_down(a2, off);
    }
    if (lane == 0) {
        out[(size_t)node*3 + 0] = a0 + b2[0];
        out[(size_t)node*3 + 1] = a1 + b2[1];
        out[(size_t)node*3 + 2] = a2 + b2[2];
    }
}

extern "C" void kernel_launch(void* const* d_in, const int* in_sizes, int n_in,
                              void* d_out, int out_size, void* d_ws, size_t ws_size,
                              hipStream_t stream) {
    const float* pos   = (const float*)d_in[0];
    const float* timeg = (const float*)d_in[1];
    const float* cell  = (const float*)d_in[2];
    const float* wemb  = (const float*)d_in[3];
    const float* r1w0  = (const float*)d_in[4];
    const float* r1b0  = (const float*)d_in[5];
    const float* r1w1  = (const float*)d_in[6];
    const float* r1b1  = (const float*)d_in[7];
    const float* r1w2  = (const float*)d_in[8];
    const float* r1b2  = (const float*)d_in[9];
    const float* r1w3  = (const float*)d_in[10];
    const float* r1b3  = (const float*)d_in[11];
    const float* l0    = (const float*)d_in[12];
    const float* l1    = (const float*)d_in[13];
    const float* l2    = (const float*)d_in[14];
    const float* r2w0  = (const float*)d_in[15];
    const float* r2b0  = (const float*)d_in[16];
    const float* r2w1  = (const float*)d_in[17];
    const float* r2b1  = (const float*)d_in[18];
    const float* r2w2  = (const float*)d_in[19];
    const float* r2b2  = (const float*)d_in[20];
    const float* r2w3  = (const float*)d_in[21];
    const float* r2b3  = (const float*)d_in[22];
    const float* mix2  = (const float*)d_in[23];
    const float* mw0   = (const float*)d_in[24];
    const float* mb0   = (const float*)d_in[25];
    const float* mw1   = (const float*)d_in[26];
    const float* mb1   = (const float*)d_in[27];
    const float* mw2   = (const float*)d_in[28];
    const float* mb2   = (const float*)d_in[29];

    float* ws    = (float*)d_ws;
    float* rad   = ws;                                   // 1,048,576 f
    float* Y1    = rad   + (size_t)NPAIR*8;              //   393,216 f
    float* Y2    = Y1    + (size_t)NPAIR*3;              //   655,360 f
    float* maskf = Y2    + (size_t)NPAIR*5;              //   131,072 f
    float* h1    = maskf + (size_t)NPAIR;                //   262,144 f
    float* v1    = h1    + (size_t)B_*N_*K_;             //   786,432 f
    short* featsb = (short*)(v1 + (size_t)B_*N_*3*K_);   // 1,441,792 sh (2048x704)
    short* prep  = featsb + (size_t)2048*704;            //   655,360 sh
    short* w1T_1 = prep;
    short* w2T_1 = prep + 4096;
    short* w1T_2 = prep + 8192;
    short* w2T_2 = prep + 12288;
    short* w3T_2 = prep + 16384;
    short* wT0   = prep + 32768;     // [512][704]
    short* wT1   = prep + 393216;    // [512][512]
    // final-MLP activations alias dead geometry buffers (sequenced after pass2):
    short* h0bb = (short*)rad;       // 2048x512 bf16 = 2 MB <= rad (4 MB)
    short* h1bb = (short*)Y2;        // 2048x512 bf16 = 2 MB <= Y2 (2.6 MB)

    prep_kernel<<<(655360 + 255)/256, 256, 0, stream>>>(
        r1w1, r1w2, r2w1, r2w2, r2w3, mw0, mw1, prep);
    geom_kernel<<<NPAIR/256, 256, 0, stream>>>(pos, cell, rad, Y1, Y2, maskf);
    pass1_kernel<<<B_*N_, 256, 0, stream>>>(rad, Y1, Y2, maskf, wemb,
        r1w0, r1b0, w1T_1, r1b1, w2T_1, r1b2, r1w3, r1b3, l0, l1, l2, timeg,
        h1, v1, featsb);
    pass2_kernel<<<B_*N_, 256, 0, stream>>>(rad, Y1, maskf,
        r2w0, r2b0, w1T_2, r2b1, w2T_2, r2b2, w3T_2, r2b3, mix2, h1, v1, featsb);
    dim3 g0(32, 8);
    gemm_mfma_kernel<<<g0, 256, 0, stream>>>(featsb, 704, wT0, 704, 704, mb0, h0bb, 512);
    gemm_mfma_kernel<<<g0, 256, 0, stream>>>(h0bb, 512, wT1, 512, 512, mb1, h1bb, 512);
    final3_kernel<<<B_*N_, 64, 0, stream>>>(h1bb, mw2, mb2, (float*)d_out);
}